// Round 10
// baseline (2325.726 us; speedup 1.0000x reference)
//
#include <hip/hip_runtime.h>

#define BB 64
#define TT 512
#define EE 512
#define RR 2048
#define RCOL 64   // columns per scan workgroup (32 LDS + 32 register-resident)
#define RPG 16    // rows (batch) per group
#define NWGS 128  // 4 groups x 32 col-WGs
#define FPAD 16   // flag padding: 16 u32 = 64 B/flag
#define SPIN_CAP (1 << 20)   // watchdog: fail fast instead of hanging

typedef _Float16 f16;
typedef f16 f16x8 __attribute__((ext_vector_type(8)));
typedef float f32x4 __attribute__((ext_vector_type(4)));

__device__ __forceinline__ void gload16(const void* g, void* l) {
  __builtin_amdgcn_global_load_lds(
      (const __attribute__((address_space(1))) void*)g,
      (__attribute__((address_space(3))) void*)l, 16, 0, 0);
}

__device__ __forceinline__ float fast_tanh(float v) {
  float e = __expf(2.0f * v);
  return 1.0f - 2.0f / (e + 1.0f);
}

// write-through device-coherent 2B store (R2-R7 proven)
__device__ __forceinline__ void storeS(f16* p, f16 h) {
  union { f16 h; unsigned short s; } u;
  u.h = h;
  __hip_atomic_store((unsigned short*)p, u.s, __ATOMIC_RELAXED, __HIP_MEMORY_SCOPE_AGENT);
}

__device__ __forceinline__ unsigned flag_ld(const unsigned* p) {
  return __hip_atomic_load(p, __ATOMIC_RELAXED, __HIP_MEMORY_SCOPE_AGENT);
}
__device__ __forceinline__ void flag_st(unsigned* p, unsigned v) {
  __hip_atomic_store(p, v, __ATOMIC_RELAXED, __HIP_MEMORY_SCOPE_AGENT);
}

// 8 sc0 (L1-bypass, L2-served) 16B loads, imm offsets 0..448 (R5-R7 proven)
__device__ __forceinline__ void issue8(f16x8* dst, unsigned voff, const f16* sbase) {
#pragma unroll
  for (int i = 0; i < 8; ++i)
    asm volatile("global_load_dwordx4 %0, %1, %2 offset:%c3 sc0"
                 : "=v"(dst[i]) : "v"(voff), "s"(sbase), "i"(64 * i) : "memory");
}

template <int N>
__device__ __forceinline__ void wait_vm() {
  asm volatile("s_waitcnt vmcnt(%c0)" :: "i"(N) : "memory");
  __builtin_amdgcn_sched_barrier(0);   // rule #18
}

// ---------------- prep kernels ----------------

__global__ void prep_emb(const int* __restrict__ x, const float* __restrict__ ew,
                         f16* __restrict__ emb) {
  const int row = blockIdx.x;            // token index (b*T + t)
  const int tok = x[row];
  const float4* src = (const float4*)(ew + (size_t)tok * EE);
  f16* dst = emb + (size_t)row * EE;
  const int i = threadIdx.x;             // 128 threads, 4 f16 each
  float4 v = src[i];
  union { f16 h[4]; unsigned long long u; } p;
  p.h[0] = (f16)v.x; p.h[1] = (f16)v.y; p.h[2] = (f16)v.z; p.h[3] = (f16)v.w;
  ((unsigned long long*)dst)[i] = p.u;
}

__global__ void prep_winT(const float* __restrict__ Win, f16* __restrict__ WinT) {
  const int i = blockIdx.x * blockDim.x + threadIdx.x;  // over EE*RR
  if (i < EE * RR) {
    const int k = i / RR, n = i % RR;
    WinT[(size_t)n * EE + k] = (f16)Win[i];
  }
}

// ---------------- projection GEMM: U[t][b][n] = emb[b,t,:] @ Win[:,n] ----------------

__launch_bounds__(256, 1)
__global__ void proj_gemm(const f16* __restrict__ A, const f16* __restrict__ Bt,
                          float* __restrict__ U) {
  __shared__ f16 As[128 * 32];
  __shared__ f16 Bs[128 * 32];
  const int tid = threadIdx.x;
  const int wv = tid >> 6, l = tid & 63;
  const int m0 = blockIdx.x * 128, n0 = blockIdx.y * 128;
  const int wm = wv >> 1, wn = wv & 1;
  const int srow = tid >> 2, sc = tid & 3;
  const int r = l & 15, kb = l >> 4;
  f32x4 acc[4][4] = {};

  for (int k0 = 0; k0 < EE; k0 += 32) {
    __syncthreads();
#pragma unroll
    for (int q = 0; q < 2; ++q) {
      const int row = q * 64 + srow;
      const int cc = sc ^ (row & 3);
      gload16(A + (size_t)(m0 + row) * EE + k0 + cc * 8,
              (char*)As + q * 4096 + wv * 1024);
      gload16(Bt + (size_t)(n0 + row) * EE + k0 + cc * 8,
              (char*)Bs + q * 4096 + wv * 1024);
    }
    __syncthreads();
    f16x8 af[4], bf[4];
#pragma unroll
    for (int mi = 0; mi < 4; ++mi) {
      const int row = wm * 64 + mi * 16 + r;
      af[mi] = *(const f16x8*)&As[row * 32 + ((kb ^ (row & 3)) * 8)];
    }
#pragma unroll
    for (int ni = 0; ni < 4; ++ni) {
      const int row = wn * 64 + ni * 16 + r;
      bf[ni] = *(const f16x8*)&Bs[row * 32 + ((kb ^ (row & 3)) * 8)];
    }
#pragma unroll
    for (int mi = 0; mi < 4; ++mi)
#pragma unroll
      for (int ni = 0; ni < 4; ++ni)
        acc[mi][ni] = __builtin_amdgcn_mfma_f32_16x16x32_f16(af[mi], bf[ni], acc[mi][ni], 0, 0, 0);
  }
  const int rb = kb * 4;
#pragma unroll
  for (int mi = 0; mi < 4; ++mi)
#pragma unroll
    for (int ni = 0; ni < 4; ++ni)
#pragma unroll
      for (int j = 0; j < 4; ++j) {
        const int m = m0 + wm * 64 + mi * 16 + rb + j;   // token index (b*512 + t)
        const int n = n0 + wn * 64 + ni * 16 + r;
        const int b = m >> 9, t = m & 511;
        __builtin_nontemporal_store(acc[mi][ni][j], &U[(size_t)(t * BB + b) * RR + n]);
      }
}

// ---------------- the sequential reservoir scan ----------------
// R6 lineage (proven): 4 batch-groups, write-through S, sc0 cached A-loads,
// per-XCD L2 invalidate + fflag, chunk flags polled per-wave. New here:
// * 64 cols/WG (32 via LDS chunk layout + 32 as register-resident B-frags)
//   -> only 32 WGs/group: max-of-32 straggler tail, half the flag traffic,
//   half the per-XCD L2 A-redundancy. Grid = 128 WGs (1/CU, LDS-capped).
// * fence duty rotates: WG with wg>>3 == tau&15 fences its XCD at step tau
//   (any WG on the XCD may fence; invalidates are always correctness-safe).
// * fflag confirm folded into the octet poll (lane 4), no extra barrier.
// Correctness never depends on WG->XCD placement (R8/R9 lesson): fence
// coverage uses the wg&7 heuristic exactly as R5-R7 (passing), flags and S
// go through L3 (coherence point). All spins watchdogged.

__launch_bounds__(512, 2)
__global__ void scan_kernel(const float* __restrict__ R, const float* __restrict__ U,
                            f16* __restrict__ S, unsigned* __restrict__ flg,
                            unsigned* __restrict__ fflag) {
  __shared__ __align__(16) char ldsbuf[32 * RR * 2 + 16 * 1040];  // 128K Rt + reduce buf
  f16* Rt = (f16*)ldsbuf;
  const char* RtB = (const char*)ldsbuf;

  const int wg = blockIdx.x;
  const int xcd = wg & 7;                        // heuristic (perf + fence bucket)
  const int grp = xcd >> 1;                      // group on XCD pair
  const int cw = ((wg >> 3) << 1) | (wg & 1);    // 0..31 within group
  const int nbase = cw * RCOL;
  const int rbase = grp * RPG;
  const int tid = threadIdx.x;
  const int wv = tid >> 6, l = tid & 63;
  unsigned* gflags = flg + (size_t)grp * 32 * FPAD;
  unsigned* myflag = gflags + cw * FPAD;
  unsigned* myff = fflag + xcd * FPAD;

  // tau = 1: state_1 = tanh(u_0) on own 16x64 patch (2 cols/thread)
  const int mm = tid >> 5, cc = tid & 31;        // row-in-group, col 0..31
  {
    f16 h0 = (f16)fast_tanh(U[(size_t)(rbase + mm) * RR + nbase + cc]);
    f16 h1 = (f16)fast_tanh(U[(size_t)(rbase + mm) * RR + nbase + 32 + cc]);
    storeS(&S[(size_t)(BB * RR) + (size_t)(rbase + mm) * RR + nbase + cc], h0);
    storeS(&S[(size_t)(BB * RR) + (size_t)(rbase + mm) * RR + nbase + 32 + cc], h1);
  }
  __syncthreads();                               // drains stores
  if (tid == 0) flag_st(myflag, 1u);

  const int r = l & 15, kb = l >> 4;
  const int kblk = (wv + cw) & 7;          // wave's k-octet (rotated)
  const int bb0 = (r * 4 + kb) * 16;       // byte within 1024B chunk row

  // ---- prologue phase A: cols nbase+32..+63 -> LDS, lift B-frags to regs ----
  {
    const int c = tid & 31, kst = tid >> 5;
    for (int k = kst; k < RR; k += 16) {
      const float v = R[(size_t)k * RR + nbase + 32 + c];
      const int idx = ((k >> 5) << 10) + ((c >> 4) << 9) +
                      (((c & 15) << 2) + ((k >> 3) & 3)) * 8 + (k & 7);
      Rt[idx] = (f16)v;
    }
  }
  __syncthreads();
  f16x8 breg[2][8];
#pragma unroll
  for (int nt = 0; nt < 2; ++nt)
#pragma unroll
    for (int ks = 0; ks < 8; ++ks)
      breg[nt][ks] = *(const f16x8*)(RtB + ((kblk << 3) + ks) * 2048 + nt * 1024 + bb0);
  __syncthreads();
  // ---- prologue phase B: cols nbase..+31 -> LDS (permanent) ----
  {
    const int c = tid & 31, kst = tid >> 5;
    for (int k = kst; k < RR; k += 16) {
      const float v = R[(size_t)k * RR + nbase + c];
      const int idx = ((k >> 5) << 10) + ((c >> 4) << 9) +
                      (((c & 15) << 2) + ((k >> 3) & 3)) * 8 + (k & 7);
      Rt[idx] = (f16)v;
    }
  }
  __syncthreads();

  // A: row = rbase + r, k = kblk*256 + kb*8 (+ks*32 via imm)
  const unsigned voffA = (unsigned)((((rbase + r) * RR) + (kblk << 8) + kb * 8) * 2);
  // combined poll: lanes !=4 poll own octet's 4 producer chunks; lane 4 fflag
  const unsigned* pollp = (l == 4) ? myff : &gflags[(size_t)(kblk * 4 + (l & 3)) * FPAD];
  // reduce-read coords for (mm, cc)
  const int ntr = cc >> 4;
  const int lred = (cc & 15) | ((mm >> 2) << 4);
  const int jred = mm & 3;

  f16x8 abuf[8];

  for (int tau = 2; tau <= TT; ++tau) {
    const f16* sprev = S + (size_t)((tau - 1) & 1) * (BB * RR);
    f16* snext = S + (size_t)(tau & 1) * (BB * RR);
    const unsigned need = (unsigned)(tau - 1);
    const unsigned thr = (l == 4) ? (unsigned)tau : need;

    // u for both output cols (HBM latency hides under poll+MFMA)
    const float uval0 = __builtin_nontemporal_load(
        &U[(size_t)(tau - 1) * (BB * RR) + (size_t)(rbase + mm) * RR + nbase + cc]);
    const float uval1 = __builtin_nontemporal_load(
        &U[(size_t)(tau - 1) * (BB * RR) + (size_t)(rbase + mm) * RR + nbase + 32 + cc]);

    // rotating fencer: one WG per XCD invalidates L2 and publishes fflag=tau
    if ((wg >> 3) == (tau & 15) && wv == 0) {
      __builtin_amdgcn_fence(__ATOMIC_ACQUIRE, "agent");
      if (l == 0) flag_st(myff, (unsigned)tau);
    }

    // per-wave poll: 4 producer chunk flags + fflag, one loop, watchdogged
    {
      unsigned fv = flag_ld(pollp);
      int gd = 0;
      while (!__all(fv >= thr) && ++gd < SPIN_CAP) {
        __builtin_amdgcn_s_sleep(1);
        fv = flag_ld(pollp);
      }
    }

    // 8 sc0 A-loads for this wave's k-octet
    issue8(abuf, voffA, sprev);

    f32x4 acc0 = {0.f, 0.f, 0.f, 0.f}, acc1 = {0.f, 0.f, 0.f, 0.f};
    f32x4 acc2 = {0.f, 0.f, 0.f, 0.f}, acc3 = {0.f, 0.f, 0.f, 0.f};
#define KSTEP(ks)                                                              \
  {                                                                            \
    const int kc = (kblk << 3) + (ks);                                         \
    f16x8 b0 = *(const f16x8*)(RtB + kc * 2048 + bb0);                         \
    f16x8 b1 = *(const f16x8*)(RtB + kc * 2048 + 1024 + bb0);                  \
    acc0 = __builtin_amdgcn_mfma_f32_16x16x32_f16(abuf[ks], b0, acc0, 0, 0, 0);\
    acc1 = __builtin_amdgcn_mfma_f32_16x16x32_f16(abuf[ks], b1, acc1, 0, 0, 0);\
    acc2 = __builtin_amdgcn_mfma_f32_16x16x32_f16(abuf[ks], breg[0][ks], acc2, 0, 0, 0);\
    acc3 = __builtin_amdgcn_mfma_f32_16x16x32_f16(abuf[ks], breg[1][ks], acc3, 0, 0, 0);\
  }
    wait_vm<4>();
    KSTEP(0) KSTEP(1) KSTEP(2) KSTEP(3)
    wait_vm<0>();
    KSTEP(4) KSTEP(5) KSTEP(6) KSTEP(7)
#undef KSTEP

    // ---- 2-pass 8-way reduce through the 16.25KB padded buffer ----
    char* red = ldsbuf + 32 * RR * 2;
    *(f32x4*)(red + (wv * 2 + 0) * 1040 + l * 16) = acc0;
    *(f32x4*)(red + (wv * 2 + 1) * 1040 + l * 16) = acc1;
    __syncthreads();
    {
      float s = 0.f;
#pragma unroll
      for (int w = 0; w < 8; ++w)
        s += *(const float*)(red + (w * 2 + ntr) * 1040 + lred * 16 + jred * 4);
      storeS(&snext[(size_t)(rbase + mm) * RR + nbase + cc],
             (f16)fast_tanh(s + uval0));
    }
    __syncthreads();
    *(f32x4*)(red + (wv * 2 + 0) * 1040 + l * 16) = acc2;
    *(f32x4*)(red + (wv * 2 + 1) * 1040 + l * 16) = acc3;
    __syncthreads();
    {
      float s = 0.f;
#pragma unroll
      for (int w = 0; w < 8; ++w)
        s += *(const float*)(red + (w * 2 + ntr) * 1040 + lred * 16 + jred * 4);
      storeS(&snext[(size_t)(rbase + mm) * RR + nbase + 32 + cc],
             (f16)fast_tanh(s + uval1));
    }
    __syncthreads();                       // drains all stores (both passes)
    if (tid == 0) flag_st(myflag, (unsigned)tau);
  }
}

// ---------------- LayerNorm ----------------

__launch_bounds__(256, 1)
__global__ void ln_kernel(const f16* __restrict__ Sfin, const float* __restrict__ gamma,
                          const float* __restrict__ beta, float* __restrict__ out) {
  const int b = blockIdx.x;
  const int tid = threadIdx.x;
  const f16* row = Sfin + (size_t)b * RR;
  float vals[8];
  float lsum = 0.f, lsq = 0.f;
#pragma unroll
  for (int i = 0; i < 8; ++i) {
    float v = (float)row[tid + i * 256];
    vals[i] = v; lsum += v; lsq += v * v;
  }
#pragma unroll
  for (int off = 32; off >= 1; off >>= 1) {
    lsum += __shfl_xor(lsum, off);
    lsq  += __shfl_xor(lsq, off);
  }
  __shared__ float ps[4], pq[4];
  __shared__ float mu_s, rstd_s;
  const int wv = tid >> 6, l = tid & 63;
  if (l == 0) { ps[wv] = lsum; pq[wv] = lsq; }
  __syncthreads();
  if (tid == 0) {
    float s = 0.f, q = 0.f;
    for (int i = 0; i < 4; ++i) { s += ps[i]; q += pq[i]; }
    const float mu = s / RR;
    const float var = q / RR - mu * mu;
    mu_s = mu; rstd_s = rsqrtf(var + 1e-5f);
  }
  __syncthreads();
  const float mu = mu_s, rstd = rstd_s;
#pragma unroll
  for (int i = 0; i < 8; ++i) {
    const int idx = tid + i * 256;
    out[(size_t)b * RR + idx] = (vals[i] - mu) * rstd * gamma[idx] + beta[idx];
  }
}

// ---------------- launch ----------------

extern "C" void kernel_launch(void* const* d_in, const int* in_sizes, int n_in,
                              void* d_out, int out_size, void* d_ws, size_t ws_size,
                              hipStream_t stream) {
  const int*   x     = (const int*)d_in[0];
  const float* ew    = (const float*)d_in[1];
  const float* Rm    = (const float*)d_in[2];
  const float* Win   = (const float*)d_in[3];
  const float* gamma = (const float*)d_in[4];
  const float* beta  = (const float*)d_in[5];

  const size_t U_OFF   = 0;                           // fp32  512*64*2048*4
  const size_t EMB_OFF = 268435456;                   // fp16  32768*512*2
  const size_t WT_OFF  = EMB_OFF + 33554432;          // fp16  2048*512*2
  const size_t S_OFF   = WT_OFF + 2097152;            // fp16  2*64*2048*2
  const size_t FLG_OFF = S_OFF + 524288;              // u32   4*32 flags x 64B
  const size_t FF_OFF  = FLG_OFF + 8192;              // u32   8 x 64B
  const size_t NEED    = FF_OFF + 1024;
  if (ws_size < NEED) {
    hipMemsetAsync(d_out, 0, (size_t)out_size * 4, stream);
    return;
  }
  char* ws = (char*)d_ws;
  float*    Ubuf  = (float*)(ws + U_OFF);
  f16*      emb   = (f16*)(ws + EMB_OFF);
  f16*      WinT  = (f16*)(ws + WT_OFF);
  f16*      Sbuf  = (f16*)(ws + S_OFF);
  unsigned* flg   = (unsigned*)(ws + FLG_OFF);
  unsigned* fflag = (unsigned*)(ws + FF_OFF);

  hipMemsetAsync(flg, 0, 8192 + 1024, stream);   // group flags + fence flags
  prep_emb<<<BB * TT, 128, 0, stream>>>(x, ew, emb);
  prep_winT<<<(EE * RR) / 256, 256, 0, stream>>>(Win, WinT);
  proj_gemm<<<dim3((BB * TT) / 128, RR / 128), 256, 0, stream>>>(emb, WinT, Ubuf);
  scan_kernel<<<NWGS, 512, 0, stream>>>(Rm, Ubuf, Sbuf, flg, fflag);
  // state_512 lives at instance 512&1 == 0
  ln_kernel<<<BB, 256, 0, stream>>>(Sbuf, gamma, beta, (float*)d_out);
}